// Round 1
// baseline (1230.651 us; speedup 1.0000x reference)
//
#include <hip/hip_runtime.h>

// Problem constants (B,H,L,D) = (2,16,2048,128), all fp32.
constexpr int Bc = 2, Hc = 16, Lc = 2048, Dc = 128;
constexpr int BHc = Bc * Hc;                        // 32
constexpr float RSCALE = 0.08838834764831845f;      // 1/sqrt(128)
constexpr size_t OUT_ELEMS = (size_t)BHc * Lc * Dc; // 8388608, start of attn_weight region
constexpr size_t SPLIT_ELEMS = (size_t)BHc * Lc * Dc; // elems per split array
constexpr size_t WS_NEED = SPLIT_ELEMS * 2 * 6;     // Qh,Ql,Kh,Kl,Vth,Vtl bf16 = 100.7MB

typedef float  f32x4 __attribute__((ext_vector_type(4)));
typedef short  s16x8 __attribute__((ext_vector_type(8)));

#define AS1(p) (const __attribute__((address_space(1))) void*)(p)
#define AS3(p) (__attribute__((address_space(3))) void*)(p)

// ---------------------------------------------------------------------------
// fp32 -> bf16 hi/lo split (RNE). hi+lo reproduces x to ~2^-17 relative.
// ---------------------------------------------------------------------------
__device__ __forceinline__ ushort bf16_rne(float x) {
    unsigned u = __float_as_uint(x);
    return (ushort)((u + 0x7FFFu + ((u >> 16) & 1u)) >> 16);
}
__device__ __forceinline__ void split1(float x, ushort& h, ushort& l) {
    ushort hb = bf16_rne(x);
    float hf = __uint_as_float((unsigned)hb << 16);
    h = hb;
    l = bf16_rne(x - hf);
}

// ---------------------------------------------------------------------------
// K0a: elementwise split of Q or K into bf16 hi/lo arrays.
// ---------------------------------------------------------------------------
__global__ __launch_bounds__(256)
void k_split(const float* __restrict__ x, ushort* __restrict__ h, ushort* __restrict__ l)
{
    const int n4 = (int)(SPLIT_ELEMS / 4);
    const int stride = gridDim.x * blockDim.x;
    for (int i = blockIdx.x * blockDim.x + threadIdx.x; i < n4; i += stride) {
        float4 v = ((const float4*)x)[i];
        ushort4 hh, ll;
        split1(v.x, hh.x, ll.x); split1(v.y, hh.y, ll.y);
        split1(v.z, hh.z, ll.z); split1(v.w, hh.w, ll.w);
        ((ushort4*)h)[i] = hh;
        ((ushort4*)l)[i] = ll;
    }
}

// ---------------------------------------------------------------------------
// K0b: V (bh,L,D) -> Vt (bh,D,L) transposed + split to bf16 hi/lo.
// One block per (64 k-rows, bh). LDS-tile transpose.
// ---------------------------------------------------------------------------
__global__ __launch_bounds__(256)
void k_vsplit(const float* __restrict__ V, ushort* __restrict__ Vth, ushort* __restrict__ Vtl)
{
    __shared__ float Vs[64][132];   // pad 128->132 (x16B aligned rows, conflict-light)
    const int kt = blockIdx.x, bh = blockIdx.y;
    const int k0 = kt * 64;
    const int tid = threadIdx.x;
    const float* Vb = V + ((size_t)bh * Lc + k0) * Dc;

#pragma unroll
    for (int i = 0; i < 8; i++) {
        int u = tid + 256 * i;          // 0..2047 float4 units
        int row = u >> 5, c4 = u & 31;  // 64 rows x 32 float4
        float4 v = *(const float4*)(Vb + (size_t)row * Dc + c4 * 4);
        *(float4*)&Vs[row][c4 * 4] = v;
    }
    __syncthreads();

    const int d = tid >> 1, part = tid & 1;  // d 0..127, 32 k each
    size_t off = ((size_t)bh * Dc + d) * Lc + k0 + part * 32;
#pragma unroll
    for (int j4 = 0; j4 < 8; j4++) {
        ushort4 hh, ll;
        split1(Vs[part * 32 + j4 * 4 + 0][d], hh.x, ll.x);
        split1(Vs[part * 32 + j4 * 4 + 1][d], hh.y, ll.y);
        split1(Vs[part * 32 + j4 * 4 + 2][d], hh.z, ll.z);
        split1(Vs[part * 32 + j4 * 4 + 3][d], hh.w, ll.w);
        *(ushort4*)(Vth + off + j4 * 4) = hh;
        *(ushort4*)(Vtl + off + j4 * 4) = ll;
    }
}

// ---------------------------------------------------------------------------
// K1 (MFMA): raw scores S[bh][q][k] = (Q·K^T)*(1 + A*wA + D*wD)*RSCALE
// 128x128 tile, 4 waves (2x2), per-wave 4x4 frags of 16x16x32 bf16 MFMA.
// Split-bf16: acc = Qh·Kh + Qh·Kl + Ql·Kh (fp32 accumulate).
// ---------------------------------------------------------------------------
__global__ __launch_bounds__(256)
void k_scores_mfma(const ushort* __restrict__ Qh, const ushort* __restrict__ Ql,
                   const ushort* __restrict__ Kh, const ushort* __restrict__ Kl,
                   const float* __restrict__ Ag, const float* __restrict__ Dg,
                   const float* __restrict__ wAg, const float* __restrict__ wDg,
                   float* __restrict__ Sg)
{
    __shared__ ushort Qhs[128 * 32], Qls[128 * 32], Khs[128 * 32], Kls[128 * 32];

    const int kt = blockIdx.x, qt = blockIdx.y, bh = blockIdx.z;
    const int b = bh >> 4, h = bh & 15;
    const int q0 = qt * 128, k0 = kt * 128;
    const int tid = threadIdx.x;
    const int lane = tid & 63, wid = tid >> 6;
    const int wr = wid >> 1, wc = wid & 1;

    const ushort* Qhb = Qh + ((size_t)bh * Lc + q0) * Dc;
    const ushort* Qlb = Ql + ((size_t)bh * Lc + q0) * Dc;
    const ushort* Khb = Kh + ((size_t)bh * Lc + k0) * Dc;
    const ushort* Klb = Kl + ((size_t)bh * Lc + k0) * Dc;

    // Staging geometry: unit u = tid + 256*i (i<2); row=u>>2, seg=u&3 (8 bf16 = 16B).
    // LDS dest is linear u*16B => wave-uniform base + lane*16 as global_load_lds requires.
    const int u0 = tid, u1 = tid + 256;
    const size_t g0 = (size_t)(u0 >> 2) * Dc + (u0 & 3) * 8;
    const size_t g1 = (size_t)(u1 >> 2) * Dc + (u1 & 3) * 8;
    const int l0 = u0 * 8, l1 = u1 * 8;   // ushort offsets

    f32x4 acc[4][4];
#pragma unroll
    for (int m = 0; m < 4; m++)
#pragma unroll
        for (int n = 0; n < 4; n++) acc[m][n] = (f32x4){0.f, 0.f, 0.f, 0.f};

    const int r15 = lane & 15, gkk = (lane >> 4) * 8;

    for (int c = 0; c < 4; c++) {        // D chunks of 32
        const int co = c * 32;
        __builtin_amdgcn_global_load_lds(AS1(Qhb + g0 + co), AS3(&Qhs[l0]), 16, 0, 0);
        __builtin_amdgcn_global_load_lds(AS1(Qhb + g1 + co), AS3(&Qhs[l1]), 16, 0, 0);
        __builtin_amdgcn_global_load_lds(AS1(Qlb + g0 + co), AS3(&Qls[l0]), 16, 0, 0);
        __builtin_amdgcn_global_load_lds(AS1(Qlb + g1 + co), AS3(&Qls[l1]), 16, 0, 0);
        __builtin_amdgcn_global_load_lds(AS1(Khb + g0 + co), AS3(&Khs[l0]), 16, 0, 0);
        __builtin_amdgcn_global_load_lds(AS1(Khb + g1 + co), AS3(&Khs[l1]), 16, 0, 0);
        __builtin_amdgcn_global_load_lds(AS1(Klb + g0 + co), AS3(&Kls[l0]), 16, 0, 0);
        __builtin_amdgcn_global_load_lds(AS1(Klb + g1 + co), AS3(&Kls[l1]), 16, 0, 0);
        __syncthreads();

        s16x8 Ahf[4], Alf[4], Bhf[4], Blf[4];
#pragma unroll
        for (int m = 0; m < 4; m++) {
            int row = wr * 64 + m * 16 + r15;
            Ahf[m] = *(const s16x8*)&Qhs[row * 32 + gkk];
            Alf[m] = *(const s16x8*)&Qls[row * 32 + gkk];
        }
#pragma unroll
        for (int n = 0; n < 4; n++) {
            int row = wc * 64 + n * 16 + r15;
            Bhf[n] = *(const s16x8*)&Khs[row * 32 + gkk];
            Blf[n] = *(const s16x8*)&Kls[row * 32 + gkk];
        }
#pragma unroll
        for (int m = 0; m < 4; m++)
#pragma unroll
            for (int n = 0; n < 4; n++) {
                acc[m][n] = __builtin_amdgcn_mfma_f32_16x16x32_bf16(Ahf[m], Bhf[n], acc[m][n], 0, 0, 0);
                acc[m][n] = __builtin_amdgcn_mfma_f32_16x16x32_bf16(Ahf[m], Blf[n], acc[m][n], 0, 0, 0);
                acc[m][n] = __builtin_amdgcn_mfma_f32_16x16x32_bf16(Alf[m], Bhf[n], acc[m][n], 0, 0, 0);
            }
        __syncthreads();
    }

    // Epilogue: multiplier + scale. C/D layout: col=lane&15, row=(lane>>4)*4+reg.
    const float wa = wAg[h], wd = wDg[h];
    const float* Arow = Ag + (size_t)b * Lc * Lc;
    const float* Drow = Dg + (size_t)b * Lc * Lc;
    float* Srow = Sg + (size_t)bh * Lc * Lc;
    const int grow = (lane >> 4) * 4;
#pragma unroll
    for (int m = 0; m < 4; m++) {
#pragma unroll
        for (int r = 0; r < 4; r++) {
            int q = q0 + wr * 64 + m * 16 + grow + r;
            size_t ro = (size_t)q * Lc + k0;
#pragma unroll
            for (int n = 0; n < 4; n++) {
                int k = wc * 64 + n * 16 + r15;
                float mult = fmaf(Arow[ro + k], wa, fmaf(Drow[ro + k], wd, 1.0f));
                Srow[ro + k] = acc[m][n][r] * mult * RSCALE;
            }
        }
    }
}

// ---------------------------------------------------------------------------
// K2: in-place row softmax over k (2048 per row). One block per row.
// ---------------------------------------------------------------------------
__global__ __launch_bounds__(256)
void k_softmax(float* __restrict__ Sg)
{
    __shared__ float red[8];
    const size_t row = blockIdx.x;
    float* Sr = Sg + row * (size_t)Lc;
    const int tid = threadIdx.x;
    const int w = tid >> 6;

    float4 v0 = *(const float4*)(Sr + tid * 4);
    float4 v1 = *(const float4*)(Sr + 1024 + tid * 4);

    float m = fmaxf(fmaxf(fmaxf(v0.x, v0.y), fmaxf(v0.z, v0.w)),
                    fmaxf(fmaxf(v1.x, v1.y), fmaxf(v1.z, v1.w)));
#pragma unroll
    for (int off = 32; off; off >>= 1) m = fmaxf(m, __shfl_xor(m, off));
    if ((tid & 63) == 0) red[w] = m;
    __syncthreads();
    m = fmaxf(fmaxf(red[0], red[1]), fmaxf(red[2], red[3]));

    float4 e0, e1;
    e0.x = __expf(v0.x - m); e0.y = __expf(v0.y - m);
    e0.z = __expf(v0.z - m); e0.w = __expf(v0.w - m);
    e1.x = __expf(v1.x - m); e1.y = __expf(v1.y - m);
    e1.z = __expf(v1.z - m); e1.w = __expf(v1.w - m);

    float s = e0.x + e0.y + e0.z + e0.w + e1.x + e1.y + e1.z + e1.w;
#pragma unroll
    for (int off = 32; off; off >>= 1) s += __shfl_xor(s, off);
    if ((tid & 63) == 0) red[4 + w] = s;
    __syncthreads();
    float l = red[4] + red[5] + red[6] + red[7];
    float rinv = 1.0f / l;

    e0.x *= rinv; e0.y *= rinv; e0.z *= rinv; e0.w *= rinv;
    e1.x *= rinv; e1.y *= rinv; e1.z *= rinv; e1.w *= rinv;
    *(float4*)(Sr + tid * 4) = e0;
    *(float4*)(Sr + 1024 + tid * 4) = e1;
}

// ---------------------------------------------------------------------------
// K3 (MFMA): out = P · V. 128q x 128d per block, K-loop over 2048 in 32-chunks.
// P (fp32 attn) reg-staged + split to bf16 hi/lo in LDS; V^T hi/lo via
// global_load_lds. acc = Ph·Vh + Ph·Vl + Pl·Vh.
// ---------------------------------------------------------------------------
__global__ __launch_bounds__(256)
void k_pv_mfma(const float* __restrict__ Pg, const ushort* __restrict__ Vth,
               const ushort* __restrict__ Vtl, float* __restrict__ Og)
{
    __shared__ ushort Phs[128 * 32], Pls[128 * 32], Vhs[128 * 32], Vls[128 * 32];

    const int qt = blockIdx.x, bh = blockIdx.y;
    const int q0 = qt * 128;
    const int tid = threadIdx.x;
    const int lane = tid & 63, wid = tid >> 6;
    const int wr = wid >> 1, wc = wid & 1;

    const float* Pb = Pg + ((size_t)bh * Lc + q0) * (size_t)Lc;
    const ushort* Vhb = Vth + (size_t)bh * Dc * Lc;
    const ushort* Vlb = Vtl + (size_t)bh * Dc * Lc;

    const int u0 = tid, u1 = tid + 256;
    const size_t vg0 = (size_t)(u0 >> 2) * Lc + (u0 & 3) * 8;  // Vt row=d, 8 bf16 segs
    const size_t vg1 = (size_t)(u1 >> 2) * Lc + (u1 & 3) * 8;
    const int vl0 = u0 * 8, vl1 = u1 * 8;

    f32x4 acc[4][4];
#pragma unroll
    for (int m = 0; m < 4; m++)
#pragma unroll
        for (int n = 0; n < 4; n++) acc[m][n] = (f32x4){0.f, 0.f, 0.f, 0.f};

    const int r15 = lane & 15, gkk = (lane >> 4) * 8;

    for (int k0 = 0; k0 < Lc; k0 += 32) {
        // V^T hi/lo chunk (128 d-rows x 32 k) via async global->LDS
        __builtin_amdgcn_global_load_lds(AS1(Vhb + vg0 + k0), AS3(&Vhs[vl0]), 16, 0, 0);
        __builtin_amdgcn_global_load_lds(AS1(Vhb + vg1 + k0), AS3(&Vhs[vl1]), 16, 0, 0);
        __builtin_amdgcn_global_load_lds(AS1(Vlb + vg0 + k0), AS3(&Vls[vl0]), 16, 0, 0);
        __builtin_amdgcn_global_load_lds(AS1(Vlb + vg1 + k0), AS3(&Vls[vl1]), 16, 0, 0);

        // P chunk (128 q-rows x 32 k) fp32 -> split -> LDS (reg-staged)
#pragma unroll
        for (int j = 0; j < 2; j++) {
            int u = tid + 256 * j;
            int row = u >> 2, s8 = u & 3;
            const float* src = Pb + (size_t)row * Lc + k0 + s8 * 8;
            float4 a = *(const float4*)(src);
            float4 bb = *(const float4*)(src + 4);
            union { ushort us[8]; s16x8 v; } H, L;
            split1(a.x,  H.us[0], L.us[0]); split1(a.y,  H.us[1], L.us[1]);
            split1(a.z,  H.us[2], L.us[2]); split1(a.w,  H.us[3], L.us[3]);
            split1(bb.x, H.us[4], L.us[4]); split1(bb.y, H.us[5], L.us[5]);
            split1(bb.z, H.us[6], L.us[6]); split1(bb.w, H.us[7], L.us[7]);
            *(s16x8*)&Phs[row * 32 + s8 * 8] = H.v;
            *(s16x8*)&Pls[row * 32 + s8 * 8] = L.v;
        }
        __syncthreads();

        s16x8 Ah[4], Al[4], Bh[4], Bl[4];
#pragma unroll
        for (int m = 0; m < 4; m++) {
            int row = wr * 64 + m * 16 + r15;
            Ah[m] = *(const s16x8*)&Phs[row * 32 + gkk];
            Al[m] = *(const s16x8*)&Pls[row * 32 + gkk];
        }
#pragma unroll
        for (int n = 0; n < 4; n++) {
            int row = wc * 64 + n * 16 + r15;   // row = d index in Vt
            Bh[n] = *(const s16x8*)&Vhs[row * 32 + gkk];
            Bl[n] = *(const s16x8*)&Vls[row * 32 + gkk];
        }
#pragma unroll
        for (int m = 0; m < 4; m++)
#pragma unroll
            for (int n = 0; n < 4; n++) {
                acc[m][n] = __builtin_amdgcn_mfma_f32_16x16x32_bf16(Ah[m], Bh[n], acc[m][n], 0, 0, 0);
                acc[m][n] = __builtin_amdgcn_mfma_f32_16x16x32_bf16(Ah[m], Bl[n], acc[m][n], 0, 0, 0);
                acc[m][n] = __builtin_amdgcn_mfma_f32_16x16x32_bf16(Al[m], Bh[n], acc[m][n], 0, 0, 0);
            }
        __syncthreads();
    }

    const int grow = (lane >> 4) * 4;
#pragma unroll
    for (int m = 0; m < 4; m++) {
#pragma unroll
        for (int r = 0; r < 4; r++) {
            int q = q0 + wr * 64 + m * 16 + grow + r;
            float* Orow = Og + ((size_t)bh * Lc + q) * Dc;
#pragma unroll
            for (int n = 0; n < 4; n++)
                Orow[wc * 64 + n * 16 + r15] = acc[m][n][r];
        }
    }
}

// ---------------------------------------------------------------------------
// Fallback fp32 path (previous verified kernels) if workspace is too small.
// ---------------------------------------------------------------------------
__global__ __launch_bounds__(256)
void k_scores(const float* __restrict__ Qg, const float* __restrict__ Kg,
              const float* __restrict__ Ag, const float* __restrict__ Dg,
              const float* __restrict__ wAg, const float* __restrict__ wDg,
              float* __restrict__ Sg)
{
    __shared__ float Qs[128][36];
    __shared__ float Ks[128][36];

    const int kt = blockIdx.x, qt = blockIdx.y, bh = blockIdx.z;
    const int b = bh >> 4, h = bh & 15;
    const int q0 = qt * 128, k0 = kt * 128;
    const int tid = threadIdx.x;
    const int tx = tid & 15, ty = tid >> 4;

    const float wa = wAg[h], wd = wDg[h];
    const float* Qb = Qg + ((size_t)bh * Lc + q0) * Dc;
    const float* Kb = Kg + ((size_t)bh * Lc + k0) * Dc;

    float acc[8][8];
#pragma unroll
    for (int i = 0; i < 8; i++)
#pragma unroll
        for (int j = 0; j < 8; j++) acc[i][j] = 0.0f;

    for (int c = 0; c < 4; c++) {
#pragma unroll
        for (int i = 0; i < 4; i++) {
            int idx = tid + 256 * i;
            int row = idx >> 3;
            int c4  = idx & 7;
            float4 qv = *(const float4*)(Qb + (size_t)row * Dc + c * 32 + c4 * 4);
            float4 kv = *(const float4*)(Kb + (size_t)row * Dc + c * 32 + c4 * 4);
            *(float4*)&Qs[row][c4 * 4] = qv;
            *(float4*)&Ks[row][c4 * 4] = kv;
        }
        __syncthreads();

#pragma unroll
        for (int d4 = 0; d4 < 8; d4++) {
            float4 a[8], bbv[8];
#pragma unroll
            for (int i = 0; i < 8; i++) a[i]   = *(const float4*)&Qs[ty + 16 * i][d4 * 4];
#pragma unroll
            for (int j = 0; j < 8; j++) bbv[j] = *(const float4*)&Ks[tx + 16 * j][d4 * 4];
#pragma unroll
            for (int i = 0; i < 8; i++)
#pragma unroll
                for (int j = 0; j < 8; j++)
                    acc[i][j] += a[i].x * bbv[j].x + a[i].y * bbv[j].y
                               + a[i].z * bbv[j].z + a[i].w * bbv[j].w;
        }
        __syncthreads();
    }

    const float* Arow = Ag + (size_t)b * Lc * Lc;
    const float* Drow = Dg + (size_t)b * Lc * Lc;
    float* Srow = Sg + (size_t)bh * Lc * Lc;
#pragma unroll
    for (int i = 0; i < 8; i++) {
        int q = q0 + ty + 16 * i;
        size_t ro = (size_t)q * Lc + k0;
#pragma unroll
        for (int j = 0; j < 8; j++) {
            int k = tx + 16 * j;
            float av = Arow[ro + k];
            float dv = Drow[ro + k];
            float mult = 1.0f + av * wa + dv * wd;
            Srow[ro + k] = acc[i][j] * mult * RSCALE;
        }
    }
}

__global__ __launch_bounds__(256)
void k_pv(const float* __restrict__ Pg, const float* __restrict__ Vg,
          float* __restrict__ Og)
{
    __shared__ float Ps[128][36];
    __shared__ float Vs[32][132];

    const int qt = blockIdx.x, bh = blockIdx.y;
    const int q0 = qt * 128;
    const int tid = threadIdx.x;
    const int tx = tid & 15, ty = tid >> 4;

    const float* Pb = Pg + ((size_t)bh * Lc + q0) * (size_t)Lc;
    const float* Vb = Vg + (size_t)bh * Lc * Dc;

    float acc[8][8];
#pragma unroll
    for (int i = 0; i < 8; i++)
#pragma unroll
        for (int j = 0; j < 8; j++) acc[i][j] = 0.0f;

    for (int k0 = 0; k0 < Lc; k0 += 32) {
#pragma unroll
        for (int i = 0; i < 4; i++) {
            int idx = tid + 256 * i;
            int rowp = idx >> 3, c4p = idx & 7;
            *(float4*)&Ps[rowp][c4p * 4] =
                *(const float4*)(Pb + (size_t)rowp * Lc + k0 + c4p * 4);
            int rowv = idx >> 5, c4v = idx & 31;
            *(float4*)&Vs[rowv][c4v * 4] =
                *(const float4*)(Vb + (size_t)(k0 + rowv) * Dc + c4v * 4);
        }
        __syncthreads();

#pragma unroll
        for (int kk4 = 0; kk4 < 8; kk4++) {
            float4 a[8];
#pragma unroll
            for (int i = 0; i < 8; i++) a[i] = *(const float4*)&Ps[ty + 16 * i][kk4 * 4];
#pragma unroll
            for (int cc = 0; cc < 4; cc++) {
                int kk = kk4 * 4 + cc;
                float4 b0 = *(const float4*)&Vs[kk][tx * 4];
                float4 b1 = *(const float4*)&Vs[kk][64 + tx * 4];
#pragma unroll
                for (int i = 0; i < 8; i++) {
                    float av = (cc == 0) ? a[i].x : (cc == 1) ? a[i].y
                             : (cc == 2) ? a[i].z : a[i].w;
                    acc[i][0] += av * b0.x; acc[i][1] += av * b0.y;
                    acc[i][2] += av * b0.z; acc[i][3] += av * b0.w;
                    acc[i][4] += av * b1.x; acc[i][5] += av * b1.y;
                    acc[i][6] += av * b1.z; acc[i][7] += av * b1.w;
                }
            }
        }
        __syncthreads();
    }

#pragma unroll
    for (int i = 0; i < 8; i++) {
        int q = q0 + ty + 16 * i;
        float* Or = Og + ((size_t)bh * Lc + q) * Dc;
        *(float4*)(Or + tx * 4)      = make_float4(acc[i][0], acc[i][1], acc[i][2], acc[i][3]);
        *(float4*)(Or + 64 + tx * 4) = make_float4(acc[i][4], acc[i][5], acc[i][6], acc[i][7]);
    }
}

// ---------------------------------------------------------------------------
extern "C" void kernel_launch(void* const* d_in, const int* in_sizes, int n_in,
                              void* d_out, int out_size, void* d_ws, size_t ws_size,
                              hipStream_t stream)
{
    const float* Q  = (const float*)d_in[0];
    const float* K  = (const float*)d_in[1];
    const float* V  = (const float*)d_in[2];
    const float* A  = (const float*)d_in[3];
    const float* Ds = (const float*)d_in[4];
    const float* wA = (const float*)d_in[5];
    const float* wD = (const float*)d_in[6];

    float* out  = (float*)d_out;            // (B,H,L,D)
    float* attn = out + OUT_ELEMS;          // (B,H,L,L)

    if (d_ws != nullptr && ws_size >= WS_NEED) {
        ushort* Qh  = (ushort*)d_ws;
        ushort* Ql  = Qh  + SPLIT_ELEMS;
        ushort* Kh  = Ql  + SPLIT_ELEMS;
        ushort* Kl  = Kh  + SPLIT_ELEMS;
        ushort* Vth = Kl  + SPLIT_ELEMS;
        ushort* Vtl = Vth + SPLIT_ELEMS;

        hipLaunchKernelGGL(k_split, dim3(1024), dim3(256), 0, stream, Q, Qh, Ql);
        hipLaunchKernelGGL(k_split, dim3(1024), dim3(256), 0, stream, K, Kh, Kl);
        hipLaunchKernelGGL(k_vsplit, dim3(Lc / 64, BHc), dim3(256), 0, stream, V, Vth, Vtl);
        hipLaunchKernelGGL(k_scores_mfma, dim3(Lc / 128, Lc / 128, BHc), dim3(256), 0, stream,
                           Qh, Ql, Kh, Kl, A, Ds, wA, wD, attn);
        hipLaunchKernelGGL(k_softmax, dim3(BHc * Lc), dim3(256), 0, stream, attn);
        hipLaunchKernelGGL(k_pv_mfma, dim3(Lc / 128, BHc), dim3(256), 0, stream, attn, Vth, Vtl, out);
    } else {
        hipLaunchKernelGGL(k_scores, dim3(Lc / 128, Lc / 128, BHc), dim3(256), 0, stream,
                           Q, K, A, Ds, wA, wD, attn);
        hipLaunchKernelGGL(k_softmax, dim3(BHc * Lc), dim3(256), 0, stream, attn);
        hipLaunchKernelGGL(k_pv, dim3(Lc / 128, BHc), dim3(256), 0, stream, attn, V, out);
    }
}